// Round 12
// baseline (228.703 us; speedup 1.0000x reference)
//
#include <hip/hip_runtime.h>
#include <math.h>

typedef __bf16 bf16_t;
typedef __bf16 bf16x8 __attribute__((ext_vector_type(8)));
typedef __bf16 bf16x4 __attribute__((ext_vector_type(4)));
typedef float f32x4 __attribute__((ext_vector_type(4)));

#define MFMA16(a, b, c) __builtin_amdgcn_mfma_f32_16x16x32_bf16((a), (b), (c), 0, 0, 0)

constexpr int Bc = 2, Nc = 2048, Dc = 1024, Hc = 16, HDc = 64;
constexpr float C1 = 0.18033688011112042f;     // 0.125 * log2(e), folded into Q at qkv epilogue
constexpr float LOG2E = 1.4426950408889634f;

// async global->LDS, 16B per lane; LDS base must be wave-uniform (HW adds lane*16)
__device__ __forceinline__ void glds16(const bf16_t* g, bf16_t* l) {
    __builtin_amdgcn_global_load_lds(
        (const __attribute__((address_space(1))) unsigned int*)g,
        (__attribute__((address_space(3))) unsigned int*)l, 16, 0, 0);
}

// ---------------------------------------------------------------------------
__device__ __forceinline__ void tr64_body(const float* __restrict__ src,
                                          bf16_t* __restrict__ dst, int R, int C,
                                          int bx, int by, bf16_t* tile, int t) {
    int r0 = by * 64, c0 = bx * 64;
    int cl = t & 63, rl = t >> 6;
#pragma unroll
    for (int p = 0; p < 16; ++p) {
        int r = p * 4 + rl;
        tile[r * 66 + cl] = (bf16_t)src[(size_t)(r0 + r) * C + c0 + cl];
    }
    __syncthreads();
#pragma unroll
    for (int p = 0; p < 16; ++p) {
        int r = p * 4 + rl;
        dst[(size_t)(c0 + r) * R + r0 + cl] = tile[cl * 66 + r];
    }
}

// ---------------------------------------------------------------------------
// Fused prep (R9/R10 form). Long-pole jobs get the LOWEST block ids.
__global__ __launch_bounds__(256) void prep(const float* __restrict__ x,
                                            bf16_t* __restrict__ Xb,
                                            const float* __restrict__ w_qkv,
                                            bf16_t* __restrict__ Wt,
                                            const float* __restrict__ w_out,
                                            bf16_t* __restrict__ WoT,
                                            float* __restrict__ pooled,
                                            const float* __restrict__ coverage,
                                            const float* __restrict__ w_ce1,
                                            const float* __restrict__ b_ce1,
                                            const float* __restrict__ w_ce2,
                                            const float* __restrict__ b_ce2,
                                            float* __restrict__ cbias) {
    __shared__ __align__(16) float smem[8768];   // 35 KB, aliased per job
    int bid = blockIdx.x, t = threadIdx.x;

    if (bid < 64) {                         // ---- coverage-bias (no gate g)
        float* w1s = smem;                  // 256
        float* b1s = smem + 256;            // 256
        float* w2s = smem + 512;            // 256*16
        float* part = smem + 4608;          // 64 rows x 65 (padded, conflict-free)
        int b = bid >> 5, n0 = (bid & 31) * 64;
        w1s[t] = w_ce1[t];
        b1s[t] = b_ce1[t];
        {
            float4* w2v = (float4*)w2s;
            const float4* g4 = (const float4*)w_ce2;
#pragma unroll
            for (int i = 0; i < 4; ++i) w2v[i * 256 + t] = g4[i * 256 + t];
        }
        __syncthreads();
        int wv = t >> 6, lane2 = t & 63;
        float c = coverage[b * 2048 + n0 + lane2];
        float acc[16];
#pragma unroll
        for (int hh = 0; hh < 16; ++hh) acc[hh] = 0.f;
        for (int jj = 0; jj < 64; ++jj) {
            int j = wv * 64 + jj;
            float tv = fmaf(c, w1s[j], b1s[j]);
            tv = tv / (1.0f + __expf(-tv));   // silu
#pragma unroll
            for (int hh = 0; hh < 16; ++hh)
                acc[hh] = fmaf(tv, w2s[j * 16 + hh], acc[hh]);
        }
#pragma unroll
        for (int hh = 0; hh < 16; ++hh) part[lane2 * 65 + wv * 16 + hh] = acc[hh];
        __syncthreads();
#pragma unroll
        for (int i = 0; i < 4; ++i) {
            int idx = t + i * 256;
            int nl = idx >> 4, hh = idx & 15;
            const float* pr = part + nl * 65 + hh;
            float s = pr[0] + pr[16] + pr[32] + pr[48];
            cbias[((size_t)b * 16 + hh) * 2048 + n0 + nl] = LOG2E * (s + b_ce2[hh]);
        }
    } else if (bid < 832) {                 // ---- transpose w_qkv
        int bb = bid - 64;
        tr64_body(w_qkv, Wt, 1024, 3072, bb % 48, bb / 48, (bf16_t*)smem, t);
    } else if (bid < 1088) {                // ---- transpose w_out
        int bb = bid - 832;
        tr64_body(w_out, WoT, 1024, 1024, bb & 15, bb >> 4, (bf16_t*)smem, t);
    } else {                                // ---- f2b + pool: 16 rows per block
        int blk = bid - 1088;               // 0..255
        int b = blk >> 7;
        int rbase = blk * 16;
        int d = t * 4;
        float s0 = 0.f, s1 = 0.f, s2 = 0.f, s3 = 0.f;
        for (int rr = 0; rr < 16; ++rr) {
            size_t off = (size_t)(rbase + rr) * 1024 + d;
            float4 v = *(const float4*)(x + off);
            s0 += v.x; s1 += v.y; s2 += v.z; s3 += v.w;
            bf16x4 o = { (bf16_t)v.x, (bf16_t)v.y, (bf16_t)v.z, (bf16_t)v.w };
            *(bf16x4*)(Xb + off) = o;
        }
        atomicAdd(&pooled[b * 1024 + d + 0], s0);
        atomicAdd(&pooled[b * 1024 + d + 1], s1);
        atomicAdd(&pooled[b * 1024 + d + 2], s2);
        atomicAdd(&pooled[b * 1024 + d + 3], s3);
    }
}

// ---------------------------------------------------------------------------
// QKV GEMM v4 (R11 form, best measured): 256x256 tile, BK=32, 512 threads =
// 8 waves (2M x 4N), acc[8][4]/wave, counted-vmcnt dbuf, 64KB LDS.
// Gate MLP at blockIdx.y == 12. Q pre-scaled by C1.
__global__ __launch_bounds__(512, 2) void qkv_gemm(const bf16_t* __restrict__ Xb,
                                                   const bf16_t* __restrict__ Wt,
                                                   bf16_t* __restrict__ Q,
                                                   bf16_t* __restrict__ Kb,
                                                   bf16_t* __restrict__ Vt,
                                                   const float* __restrict__ pooled,
                                                   const float* __restrict__ w_fg1,
                                                   const float* __restrict__ b_fg1,
                                                   const float* __restrict__ w_fg2,
                                                   float* __restrict__ hacc) {
    __shared__ __align__(16) bf16_t lds[2][16384];   // 64 KB total
    int t = threadIdx.x;

    if (blockIdx.y == 12) {                 // gate MLP: hacc[b] += silu(h_j)*w_fg2[j]
        float* red = (float*)&lds[0][0];
        int blk = blockIdx.x;               // 16 blocks: b = blk>>3, 32 j's each
        int b = blk >> 3, jb = (blk & 7) * 32;
        for (int jj = 0; jj < 32; ++jj) {
            int j = jb + jj;
            int d = t * 2;
            float p = pooled[b * 1024 + d] * w_fg1[d * 256 + j]
                    + pooled[b * 1024 + d + 1] * w_fg1[(d + 1) * 256 + j];
#pragma unroll
            for (int off = 32; off > 0; off >>= 1) p += __shfl_down(p, off);
            if ((t & 63) == 0) red[t >> 6] = p;
            __syncthreads();
            if (t == 0) {
                float s = red[0] + red[1] + red[2] + red[3]
                        + red[4] + red[5] + red[6] + red[7];
                float hj = s * (1.0f / 2048.0f) + b_fg1[j];
                hj = hj / (1.0f + __expf(-hj)); // silu
                atomicAdd(&hacc[b], hj * w_fg2[j]);
            }
            __syncthreads();
        }
        return;
    }

    int w = t >> 6, lane = t & 63;
    int l16 = lane & 15, quad = lane >> 4;
    int wm = w >> 2, wn = w & 3;            // 2M x 4N wave grid
    int m0 = blockIdx.x * 256;              // x-row base
    int n0 = blockIdx.y * 256;              // W-col base
    f32x4 acc[8][4] = {};
    int sw = (l16 >> 2) & 3;
    int cq = (quad ^ sw) * 8;

    int srow[4], ssc[4], sdst[4];
    bool sB[4];
#pragma unroll
    for (int j = 0; j < 4; ++j) {
        int off = w * 4096 + j * 1024 + lane * 16;   // byte in 32KB tile
        bool inB = off >= 16384;
        int o2 = off - (inB ? 16384 : 0);
        int row = o2 >> 6;                           // 64B per 32-k row
        int ch = (o2 >> 4) & 3;
        srow[j] = row;
        ssc[j] = ch ^ ((row >> 2) & 3);
        sB[j] = inB;
        sdst[j] = (w * 4096 + j * 1024) >> 1;        // wave-uniform elem base
    }
    auto stg = [&](int j, int k0, int bf) {
        const bf16_t* src = sB[j] ? Xb + (size_t)(m0 + srow[j]) * 1024
                                  : Wt + (size_t)(n0 + srow[j]) * 1024;
        glds16(src + k0 + ssc[j] * 8, &lds[bf][sdst[j]]);
    };

    int aB = (wm * 128 + l16) * 32 + cq;             // A frag mi at aB + mi*512
    int bB = 8192 + (wn * 64 + l16) * 32 + cq;       // B frag ni at bB + ni*512

    stg(0, 0, 0); stg(1, 0, 0); stg(2, 0, 0); stg(3, 0, 0);

#pragma unroll 1
    for (int ks = 0; ks < 32; ++ks) {
        int cb = ks & 1, k0n = (ks + 1) * 32;
        if (ks + 1 < 32) {
            stg(0, k0n, cb ^ 1); stg(1, k0n, cb ^ 1);           // outstanding: 6
            asm volatile("s_waitcnt vmcnt(2)" ::: "memory");    // tile-ks landed
        } else {
            asm volatile("s_waitcnt vmcnt(0)" ::: "memory");
        }
        __builtin_amdgcn_s_barrier();
        __builtin_amdgcn_sched_barrier(0);

        const bf16_t* L = lds[cb];
        bf16x8 Ar[4], Br[4];
#pragma unroll
        for (int mi = 0; mi < 4; ++mi) Ar[mi] = *(const bf16x8*)(L + aB + mi * 512);
#pragma unroll
        for (int ni = 0; ni < 4; ++ni) Br[ni] = *(const bf16x8*)(L + bB + ni * 512);
        __builtin_amdgcn_s_setprio(1);
#pragma unroll
        for (int mi = 0; mi < 4; ++mi)
#pragma unroll
            for (int ni = 0; ni < 4; ++ni)
                acc[mi][ni] = MFMA16(Ar[mi], Br[ni], acc[mi][ni]);
        __builtin_amdgcn_s_setprio(0);
        __builtin_amdgcn_s_barrier();
        __builtin_amdgcn_sched_barrier(0);

        if (ks + 1 < 32) { stg(2, k0n, cb ^ 1); stg(3, k0n, cb ^ 1); }
#pragma unroll
        for (int mi = 0; mi < 4; ++mi) Ar[mi] = *(const bf16x8*)(L + aB + 2048 + mi * 512);
        __builtin_amdgcn_s_setprio(1);
#pragma unroll
        for (int mi = 0; mi < 4; ++mi)
#pragma unroll
            for (int ni = 0; ni < 4; ++ni)
                acc[4 + mi][ni] = MFMA16(Ar[mi], Br[ni], acc[4 + mi][ni]);
        __builtin_amdgcn_s_setprio(0);
        __builtin_amdgcn_s_barrier();
        __builtin_amdgcn_sched_barrier(0);
    }

    int sec = n0 >> 10;
    float scq = (sec == 0) ? C1 : 1.0f;
#pragma unroll
    for (int mi = 0; mi < 8; ++mi) {
        int gc = n0 + wm * 128 + mi * 16 + quad * 4;
        int dcol = gc & 1023;
        int h = dcol >> 6, hd = dcol & 63;
#pragma unroll
        for (int ni = 0; ni < 4; ++ni) {
            int gx = m0 + wn * 64 + ni * 16 + l16;
            int b = gx >> 11, n = gx & 2047;
            size_t bh = (size_t)(b * 16 + h);
            if (sec == 2) {
#pragma unroll
                for (int r = 0; r < 4; ++r)
                    Vt[(bh * 64 + hd + r) * 2048 + n] = (bf16_t)acc[mi][ni][r];
            } else {
                bf16x4 pk = { (bf16_t)(acc[mi][ni][0] * scq), (bf16_t)(acc[mi][ni][1] * scq),
                              (bf16_t)(acc[mi][ni][2] * scq), (bf16_t)(acc[mi][ni][3] * scq) };
                bf16_t* dst = (sec == 0 ? Q : Kb);
                *(bf16x4*)(dst + (bh * 2048 + n) * 64 + hd) = pk;
            }
        }
    }
}

// ---------------------------------------------------------------------------
// Flash attention v12: KV=128 per iteration (two 64-wide subtiles reusing the
// proven swizzle), 16 iters x 2 barriers = half the sync events of v11.
// LDS 72KB: still 2 blocks/CU (grid is 512 = 2/CU anyway). Counted vmcnt(8).
// Chunked XCD mapping retained (FETCH 70.7 -> 12.5 MB in R11).
__global__ __launch_bounds__(256) void attn_k(const bf16_t* __restrict__ Q,
                                              const bf16_t* __restrict__ Kb,
                                              const bf16_t* __restrict__ Vt,
                                              const float* __restrict__ cbias,
                                              const float* __restrict__ hacc,
                                              const float* __restrict__ b_fg2,
                                              bf16_t* __restrict__ O) {
    __shared__ __align__(16) bf16_t kbuf[2][2][64 * 64];
    __shared__ __align__(16) bf16_t vbuf[2][2][64 * 64];
    __shared__ __align__(16) float ball[2048];
    int t = threadIdx.x, w = t >> 6, lane = t & 63;
    int l16 = lane & 15, quad = lane >> 4;
    int id = blockIdx.x;                    // 0..511, HW assigns XCD = id % 8
    int xcd = id & 7, slot = id >> 3;       // 64 slots per XCD
    int bh = xcd * 4 + (slot >> 4);         // 4 heads per XCD
    int xblk = slot & 15;                   // 16 q-blocks per head, same XCD
    int b = bh >> 4, h = bh & 15;
    int qa = xblk * 128 + w * 32;
    const bf16_t* Qh = Q + (size_t)bh * 2048 * 64;
    const bf16_t* Kh = Kb + (size_t)bh * 2048 * 64;
    const bf16_t* Vh = Vt + (size_t)bh * 64 * 2048;
    const float* bih = cbias + (size_t)bh * 2048;
    float g = 1.0f / (1.0f + __expf(-(hacc[b] + b_fg2[0])));

    // one-time g-scaled bias row into LDS (published by first lgkm(0)+barrier)
#pragma unroll
    for (int c = 0; c < 2; ++c) {
        float4 v = *(const float4*)(bih + c * 1024 + t * 4);
        float4 sv = { v.x * g, v.y * g, v.z * g, v.w * g };
        *(float4*)(ball + c * 1024 + t * 4) = sv;
    }

    int fb0 = w * 2048, fb1 = fb0 + 1024;   // byte ranges staged by this wave
    int f0 = fb0 + lane * 16, f1 = fb1 + lane * 16;
    int krow0 = f0 >> 7, kch0 = ((f0 >> 4) & 7) ^ (krow0 & 7);
    int krow1 = f1 >> 7, kch1 = ((f1 >> 4) & 7) ^ (krow1 & 7);

    bf16x8 qf[2][2];
#pragma unroll
    for (int qt = 0; qt < 2; ++qt)
#pragma unroll
        for (int dh = 0; dh < 2; ++dh)
            qf[qt][dh] = *(const bf16x8*)(Qh + (size_t)(qa + qt * 16 + l16) * 64 + dh * 32 + quad * 8);

    f32x4 o[2][4] = {};
    f32x4 lacc[2] = {};
    bf16x8 onesb;
#pragma unroll
    for (int i = 0; i < 8; ++i) onesb[i] = (bf16_t)1.0f;
    int swl = l16 & 7;
    int qh = quad >> 1, ql = quad & 1;

    // hoisted per-thread LDS read offsets (elements)
    int bk0 = l16 * 64 + ((quad ^ swl) * 8);
    int bk1 = l16 * 64 + (((4 + quad) ^ swl) * 8);
    int bv0 = l16 * 64 + ql * 4 + ((qh ^ swl) * 8);
    int bv1 = l16 * 64 + ql * 4 + (((2 + qh) ^ swl) * 8);
    int bv2 = l16 * 64 + ql * 4 + (((4 + qh) ^ swl) * 8);
    int bv3 = l16 * 64 + ql * 4 + (((6 + qh) ^ swl) * 8);

    // stage one 64-KV subtile: 4 vmem ops per wave (K2 + V2)
    auto stageSub = [&](int jn, bf16_t* kd, bf16_t* vd) {
        glds16(Kh + (size_t)(jn + krow0) * 64 + kch0 * 8, kd + (fb0 >> 1));
        glds16(Kh + (size_t)(jn + krow1) * 64 + kch1 * 8, kd + (fb1 >> 1));
        glds16(Vh + (size_t)krow0 * 2048 + jn + kch0 * 8, vd + (fb0 >> 1));
        glds16(Vh + (size_t)krow1 * 2048 + jn + kch1 * 8, vd + (fb1 >> 1));
    };
    // stage a full 128-KV tile: 8 vmem ops per wave
    auto stage = [&](int tile_, int bf) {
        int jn = tile_ * 128;
        stageSub(jn,      &kbuf[bf][0][0], &vbuf[bf][0][0]);
        stageSub(jn + 64, &kbuf[bf][1][0], &vbuf[bf][1][0]);
    };

    stage(0, 0);

    for (int it = 0; it < 16; ++it) {
        int sel = it & 1;
        asm volatile("s_waitcnt lgkmcnt(0)" ::: "memory");
        __builtin_amdgcn_s_barrier();            // everyone done reading buf[sel^1]
        if (it + 1 < 16) {
            stage(it + 1, sel ^ 1);              // outstanding: 16
            asm volatile("s_waitcnt vmcnt(8)" ::: "memory");   // tile-it loads done
        } else {
            asm volatile("s_waitcnt vmcnt(0)" ::: "memory");
        }
        __builtin_amdgcn_s_barrier();            // tile-it data visible to all waves
        __builtin_amdgcn_sched_barrier(0);

#pragma unroll
        for (int sub = 0; sub < 2; ++sub) {
            int j0 = it * 128 + sub * 64;
            const bf16_t* kb = &kbuf[sel][sub][0];
            const bf16_t* vb = &vbuf[sel][sub][0];

            f32x4 s[2][4];
            __builtin_amdgcn_s_setprio(1);
#pragma unroll
            for (int kt = 0; kt < 4; ++kt) {
                f32x4 bi = *(const f32x4*)(ball + j0 + kt * 16 + quad * 4);   // LDS broadcast
                bf16x8 kf0 = *(const bf16x8*)(kb + kt * 1024 + bk0);
                bf16x8 kf1 = *(const bf16x8*)(kb + kt * 1024 + bk1);
#pragma unroll
                for (int qt = 0; qt < 2; ++qt) {
                    s[qt][kt] = MFMA16(kf0, qf[qt][0], bi);
                    s[qt][kt] = MFMA16(kf1, qf[qt][1], s[qt][kt]);
                }
            }
            __builtin_amdgcn_s_setprio(0);

            bf16x8 pf[2][2];
#pragma unroll
            for (int qt = 0; qt < 2; ++qt) {
#pragma unroll
                for (int kt = 0; kt < 4; ++kt)
#pragma unroll
                    for (int r = 0; r < 4; ++r)
                        s[qt][kt][r] = __builtin_amdgcn_exp2f(s[qt][kt][r]);
#pragma unroll
                for (int pv = 0; pv < 2; ++pv) {
                    bf16x8 tmp;
#pragma unroll
                    for (int i = 0; i < 4; ++i) {
                        tmp[i]     = (bf16_t)s[qt][2 * pv][i];
                        tmp[i + 4] = (bf16_t)s[qt][2 * pv + 1][i];
                    }
                    pf[qt][pv] = tmp;
                }
            }

            __builtin_amdgcn_s_setprio(1);
#pragma unroll
            for (int qt = 0; qt < 2; ++qt) {
                lacc[qt] = MFMA16(pf[qt][0], onesb, lacc[qt]);
                lacc[qt] = MFMA16(pf[qt][1], onesb, lacc[qt]);
            }
#pragma unroll
            for (int dt = 0; dt < 4; ++dt) {
                bf16x4 va0 = *(const bf16x4*)(vb + dt * 1024 + bv0);
                bf16x4 vc0 = *(const bf16x4*)(vb + dt * 1024 + bv1);
                bf16x8 vf0 = __builtin_shufflevector(va0, vc0, 0, 1, 2, 3, 4, 5, 6, 7);
                bf16x4 va1 = *(const bf16x4*)(vb + dt * 1024 + bv2);
                bf16x4 vc1 = *(const bf16x4*)(vb + dt * 1024 + bv3);
                bf16x8 vf1 = __builtin_shufflevector(va1, vc1, 0, 1, 2, 3, 4, 5, 6, 7);
#pragma unroll
                for (int qt = 0; qt < 2; ++qt) {
                    o[qt][dt] = MFMA16(pf[qt][0], vf0, o[qt][dt]);
                    o[qt][dt] = MFMA16(pf[qt][1], vf1, o[qt][dt]);
                }
            }
            __builtin_amdgcn_s_setprio(0);
        }
    }

#pragma unroll
    for (int qt = 0; qt < 2; ++qt) {
        f32x4 rinv;
#pragma unroll
        for (int r = 0; r < 4; ++r) rinv[r] = 1.0f / lacc[qt][r];
#pragma unroll
        for (int dt = 0; dt < 4; ++dt)
#pragma unroll
            for (int r = 0; r < 4; ++r) {
                int row = qa + qt * 16 + quad * 4 + r;
                O[(size_t)(b * 2048 + row) * 1024 + h * 64 + dt * 16 + l16] =
                    (bf16_t)(o[qt][dt][r] * rinv[r]);
            }
    }
}

// ---------------------------------------------------------------------------
// out GEMM: R5 single-buffer __syncthreads form (best-measured total).
__global__ __launch_bounds__(256) void out_gemm(const bf16_t* __restrict__ A,
                                                const bf16_t* __restrict__ Wt,
                                                const float* __restrict__ bias,
                                                float* __restrict__ Cout) {
    __shared__ __align__(16) bf16_t At[128 * 32];
    __shared__ __align__(16) bf16_t Bt[128 * 32];
    int t = threadIdx.x, w = t >> 6, lane = t & 63;
    int l16 = lane & 15, quad = lane >> 4;
    int wm = w & 1, wx = w >> 1;
    int m0 = blockIdx.x * 128;
    int n0 = blockIdx.y * 128;
    f32x4 acc[4][4] = {};
    int sw = (l16 >> 2) & 3;

    for (int k0 = 0; k0 < 1024; k0 += 32) {
#pragma unroll
        for (int i = 0; i < 2; ++i) {
            int fb = i * 4096 + w * 1024;
            int f = fb + lane * 16;
            int row = f >> 6;
            int ch = (f >> 4) & 3;
            int sc = ch ^ ((row >> 2) & 3);
            glds16(Wt + (size_t)(n0 + row) * 1024 + k0 + sc * 8, At + (fb >> 1));
            glds16(A + (size_t)(m0 + row) * 1024 + k0 + sc * 8, Bt + (fb >> 1));
        }
        __syncthreads();
        bf16x8 afr[4], bfr[4];
#pragma unroll
        for (int mi = 0; mi < 4; ++mi)
            afr[mi] = *(const bf16x8*)(At + (wm * 64 + mi * 16 + l16) * 32 + ((quad ^ sw) * 8));
#pragma unroll
        for (int ni = 0; ni < 4; ++ni)
            bfr[ni] = *(const bf16x8*)(Bt + (wx * 64 + ni * 16 + l16) * 32 + ((quad ^ sw) * 8));
#pragma unroll
        for (int mi = 0; mi < 4; ++mi)
#pragma unroll
            for (int ni = 0; ni < 4; ++ni)
                acc[mi][ni] = MFMA16(afr[mi], bfr[ni], acc[mi][ni]);
        __syncthreads();
    }

#pragma unroll
    for (int mi = 0; mi < 4; ++mi) {
        int gc = n0 + wm * 64 + mi * 16 + quad * 4;
        float4 bv = *(const float4*)(bias + gc);
#pragma unroll
        for (int ni = 0; ni < 4; ++ni) {
            int gx = m0 + wx * 64 + ni * 16 + l16;
            float4 ov = { acc[mi][ni][0] + bv.x, acc[mi][ni][1] + bv.y,
                          acc[mi][ni][2] + bv.z, acc[mi][ni][3] + bv.w };
            *(float4*)(Cout + (size_t)gx * 1024 + gc) = ov;
        }
    }
}

// ---------------------------------------------------------------------------
extern "C" void kernel_launch(void* const* d_in, const int* in_sizes, int n_in,
                              void* d_out, int out_size, void* d_ws, size_t ws_size,
                              hipStream_t stream) {
    const float* x     = (const float*)d_in[0];
    const float* cov   = (const float*)d_in[1];
    const float* w_qkv = (const float*)d_in[2];
    const float* w_out = (const float*)d_in[3];
    const float* b_out = (const float*)d_in[4];
    const float* w_ce1 = (const float*)d_in[5];
    const float* b_ce1 = (const float*)d_in[6];
    const float* w_ce2 = (const float*)d_in[7];
    const float* b_ce2 = (const float*)d_in[8];
    const float* w_fg1 = (const float*)d_in[9];
    const float* b_fg1 = (const float*)d_in[10];
    const float* w_fg2 = (const float*)d_in[11];
    const float* b_fg2 = (const float*)d_in[12];

    char* ws = (char*)d_ws;
    bf16_t* Wt     = (bf16_t*)(ws);              // 3072x1024
    bf16_t* WoT    = (bf16_t*)(ws + 6291456);    // 1024x1024
    bf16_t* Xb     = (bf16_t*)(ws + 8388608);    // 4096x1024
    bf16_t* Qb     = (bf16_t*)(ws + 16777216);   // (2,16,2048,64)
    bf16_t* Kbb    = (bf16_t*)(ws + 25165824);   // (2,16,2048,64)
    bf16_t* Vt     = (bf16_t*)(ws + 33554432);   // (2,16,64,2048)
    bf16_t* Ob     = (bf16_t*)(ws + 41943040);   // (4096,1024)
    float*  pooled = (float*)(ws + 50331648);    // 2x1024 f32
    float*  hacc   = (float*)(ws + 50339840);    // 2 f32 (contiguous after pooled)
    float*  biasb  = (float*)(ws + 50340096);    // 2x16x2048 f32 (no g applied)

    hipMemsetAsync(pooled, 0, 8200, stream);
    prep<<<1344, 256, 0, stream>>>(x, Xb, w_qkv, Wt, w_out, WoT, pooled,
                                   cov, w_ce1, b_ce1, w_ce2, b_ce2, biasb);
    qkv_gemm<<<dim3(16, 13), 512, 0, stream>>>(Xb, Wt, Qb, Kbb, Vt,
                                               pooled, w_fg1, b_fg1, w_fg2, hacc);
    attn_k<<<512, 256, 0, stream>>>(Qb, Kbb, Vt, biasb, hacc, b_fg2, Ob);
    out_gemm<<<dim3(32, 8), 256, 0, stream>>>(Ob, WoT, b_out, (float*)d_out);
}

// Round 13
// 227.617 us; speedup vs baseline: 1.0048x; 1.0048x over previous
//
#include <hip/hip_runtime.h>
#include <math.h>

typedef __bf16 bf16_t;
typedef __bf16 bf16x8 __attribute__((ext_vector_type(8)));
typedef __bf16 bf16x4 __attribute__((ext_vector_type(4)));
typedef float f32x4 __attribute__((ext_vector_type(4)));

#define MFMA16(a, b, c) __builtin_amdgcn_mfma_f32_16x16x32_bf16((a), (b), (c), 0, 0, 0)

constexpr int Bc = 2, Nc = 2048, Dc = 1024, Hc = 16, HDc = 64;
constexpr float C1 = 0.18033688011112042f;     // 0.125 * log2(e), folded into Q at qkv epilogue
constexpr float LOG2E = 1.4426950408889634f;

// async global->LDS, 16B per lane; LDS base must be wave-uniform (HW adds lane*16)
__device__ __forceinline__ void glds16(const bf16_t* g, bf16_t* l) {
    __builtin_amdgcn_global_load_lds(
        (const __attribute__((address_space(1))) unsigned int*)g,
        (__attribute__((address_space(3))) unsigned int*)l, 16, 0, 0);
}

// ---------------------------------------------------------------------------
__device__ __forceinline__ void tr64_body(const float* __restrict__ src,
                                          bf16_t* __restrict__ dst, int R, int C,
                                          int bx, int by, bf16_t* tile, int t) {
    int r0 = by * 64, c0 = bx * 64;
    int cl = t & 63, rl = t >> 6;
#pragma unroll
    for (int p = 0; p < 16; ++p) {
        int r = p * 4 + rl;
        tile[r * 66 + cl] = (bf16_t)src[(size_t)(r0 + r) * C + c0 + cl];
    }
    __syncthreads();
#pragma unroll
    for (int p = 0; p < 16; ++p) {
        int r = p * 4 + rl;
        dst[(size_t)(c0 + r) * R + r0 + cl] = tile[cl * 66 + r];
    }
}

// ---------------------------------------------------------------------------
// Fused prep (R9/R10 form). Long-pole jobs get the LOWEST block ids.
__global__ __launch_bounds__(256) void prep(const float* __restrict__ x,
                                            bf16_t* __restrict__ Xb,
                                            const float* __restrict__ w_qkv,
                                            bf16_t* __restrict__ Wt,
                                            const float* __restrict__ w_out,
                                            bf16_t* __restrict__ WoT,
                                            float* __restrict__ pooled,
                                            const float* __restrict__ coverage,
                                            const float* __restrict__ w_ce1,
                                            const float* __restrict__ b_ce1,
                                            const float* __restrict__ w_ce2,
                                            const float* __restrict__ b_ce2,
                                            float* __restrict__ cbias) {
    __shared__ __align__(16) float smem[8768];   // 35 KB, aliased per job
    int bid = blockIdx.x, t = threadIdx.x;

    if (bid < 64) {                         // ---- coverage-bias (no gate g)
        float* w1s = smem;                  // 256
        float* b1s = smem + 256;            // 256
        float* w2s = smem + 512;            // 256*16
        float* part = smem + 4608;          // 64 rows x 65 (padded, conflict-free)
        int b = bid >> 5, n0 = (bid & 31) * 64;
        w1s[t] = w_ce1[t];
        b1s[t] = b_ce1[t];
        {
            float4* w2v = (float4*)w2s;
            const float4* g4 = (const float4*)w_ce2;
#pragma unroll
            for (int i = 0; i < 4; ++i) w2v[i * 256 + t] = g4[i * 256 + t];
        }
        __syncthreads();
        int wv = t >> 6, lane2 = t & 63;
        float c = coverage[b * 2048 + n0 + lane2];
        float acc[16];
#pragma unroll
        for (int hh = 0; hh < 16; ++hh) acc[hh] = 0.f;
        for (int jj = 0; jj < 64; ++jj) {
            int j = wv * 64 + jj;
            float tv = fmaf(c, w1s[j], b1s[j]);
            tv = tv / (1.0f + __expf(-tv));   // silu
#pragma unroll
            for (int hh = 0; hh < 16; ++hh)
                acc[hh] = fmaf(tv, w2s[j * 16 + hh], acc[hh]);
        }
#pragma unroll
        for (int hh = 0; hh < 16; ++hh) part[lane2 * 65 + wv * 16 + hh] = acc[hh];
        __syncthreads();
#pragma unroll
        for (int i = 0; i < 4; ++i) {
            int idx = t + i * 256;
            int nl = idx >> 4, hh = idx & 15;
            const float* pr = part + nl * 65 + hh;
            float s = pr[0] + pr[16] + pr[32] + pr[48];
            cbias[((size_t)b * 16 + hh) * 2048 + n0 + nl] = LOG2E * (s + b_ce2[hh]);
        }
    } else if (bid < 832) {                 // ---- transpose w_qkv
        int bb = bid - 64;
        tr64_body(w_qkv, Wt, 1024, 3072, bb % 48, bb / 48, (bf16_t*)smem, t);
    } else if (bid < 1088) {                // ---- transpose w_out
        int bb = bid - 832;
        tr64_body(w_out, WoT, 1024, 1024, bb & 15, bb >> 4, (bf16_t*)smem, t);
    } else {                                // ---- f2b + pool: 16 rows per block
        int blk = bid - 1088;               // 0..255
        int b = blk >> 7;
        int rbase = blk * 16;
        int d = t * 4;
        float s0 = 0.f, s1 = 0.f, s2 = 0.f, s3 = 0.f;
        for (int rr = 0; rr < 16; ++rr) {
            size_t off = (size_t)(rbase + rr) * 1024 + d;
            float4 v = *(const float4*)(x + off);
            s0 += v.x; s1 += v.y; s2 += v.z; s3 += v.w;
            bf16x4 o = { (bf16_t)v.x, (bf16_t)v.y, (bf16_t)v.z, (bf16_t)v.w };
            *(bf16x4*)(Xb + off) = o;
        }
        atomicAdd(&pooled[b * 1024 + d + 0], s0);
        atomicAdd(&pooled[b * 1024 + d + 1], s1);
        atomicAdd(&pooled[b * 1024 + d + 2], s2);
        atomicAdd(&pooled[b * 1024 + d + 3], s3);
    }
}

// ---------------------------------------------------------------------------
// QKV GEMM v4 (R11 form, best measured): 256x256 tile, BK=32, 512 threads =
// 8 waves (2M x 4N), acc[8][4]/wave, counted-vmcnt dbuf, 64KB LDS.
// Gate MLP at blockIdx.y == 12. Q pre-scaled by C1.
__global__ __launch_bounds__(512, 2) void qkv_gemm(const bf16_t* __restrict__ Xb,
                                                   const bf16_t* __restrict__ Wt,
                                                   bf16_t* __restrict__ Q,
                                                   bf16_t* __restrict__ Kb,
                                                   bf16_t* __restrict__ Vt,
                                                   const float* __restrict__ pooled,
                                                   const float* __restrict__ w_fg1,
                                                   const float* __restrict__ b_fg1,
                                                   const float* __restrict__ w_fg2,
                                                   float* __restrict__ hacc) {
    __shared__ __align__(16) bf16_t lds[2][16384];   // 64 KB total
    int t = threadIdx.x;

    if (blockIdx.y == 12) {                 // gate MLP: hacc[b] += silu(h_j)*w_fg2[j]
        float* red = (float*)&lds[0][0];
        int blk = blockIdx.x;               // 16 blocks: b = blk>>3, 32 j's each
        int b = blk >> 3, jb = (blk & 7) * 32;
        for (int jj = 0; jj < 32; ++jj) {
            int j = jb + jj;
            int d = t * 2;
            float p = pooled[b * 1024 + d] * w_fg1[d * 256 + j]
                    + pooled[b * 1024 + d + 1] * w_fg1[(d + 1) * 256 + j];
#pragma unroll
            for (int off = 32; off > 0; off >>= 1) p += __shfl_down(p, off);
            if ((t & 63) == 0) red[t >> 6] = p;
            __syncthreads();
            if (t == 0) {
                float s = red[0] + red[1] + red[2] + red[3]
                        + red[4] + red[5] + red[6] + red[7];
                float hj = s * (1.0f / 2048.0f) + b_fg1[j];
                hj = hj / (1.0f + __expf(-hj)); // silu
                atomicAdd(&hacc[b], hj * w_fg2[j]);
            }
            __syncthreads();
        }
        return;
    }

    int w = t >> 6, lane = t & 63;
    int l16 = lane & 15, quad = lane >> 4;
    int wm = w >> 2, wn = w & 3;            // 2M x 4N wave grid
    int m0 = blockIdx.x * 256;              // x-row base
    int n0 = blockIdx.y * 256;              // W-col base
    f32x4 acc[8][4] = {};
    int sw = (l16 >> 2) & 3;
    int cq = (quad ^ sw) * 8;

    int srow[4], ssc[4], sdst[4];
    bool sB[4];
#pragma unroll
    for (int j = 0; j < 4; ++j) {
        int off = w * 4096 + j * 1024 + lane * 16;   // byte in 32KB tile
        bool inB = off >= 16384;
        int o2 = off - (inB ? 16384 : 0);
        int row = o2 >> 6;                           // 64B per 32-k row
        int ch = (o2 >> 4) & 3;
        srow[j] = row;
        ssc[j] = ch ^ ((row >> 2) & 3);
        sB[j] = inB;
        sdst[j] = (w * 4096 + j * 1024) >> 1;        // wave-uniform elem base
    }
    auto stg = [&](int j, int k0, int bf) {
        const bf16_t* src = sB[j] ? Xb + (size_t)(m0 + srow[j]) * 1024
                                  : Wt + (size_t)(n0 + srow[j]) * 1024;
        glds16(src + k0 + ssc[j] * 8, &lds[bf][sdst[j]]);
    };

    int aB = (wm * 128 + l16) * 32 + cq;             // A frag mi at aB + mi*512
    int bB = 8192 + (wn * 64 + l16) * 32 + cq;       // B frag ni at bB + ni*512

    stg(0, 0, 0); stg(1, 0, 0); stg(2, 0, 0); stg(3, 0, 0);

#pragma unroll 1
    for (int ks = 0; ks < 32; ++ks) {
        int cb = ks & 1, k0n = (ks + 1) * 32;
        if (ks + 1 < 32) {
            stg(0, k0n, cb ^ 1); stg(1, k0n, cb ^ 1);           // outstanding: 6
            asm volatile("s_waitcnt vmcnt(2)" ::: "memory");    // tile-ks landed
        } else {
            asm volatile("s_waitcnt vmcnt(0)" ::: "memory");
        }
        __builtin_amdgcn_s_barrier();
        __builtin_amdgcn_sched_barrier(0);

        const bf16_t* L = lds[cb];
        bf16x8 Ar[4], Br[4];
#pragma unroll
        for (int mi = 0; mi < 4; ++mi) Ar[mi] = *(const bf16x8*)(L + aB + mi * 512);
#pragma unroll
        for (int ni = 0; ni < 4; ++ni) Br[ni] = *(const bf16x8*)(L + bB + ni * 512);
        __builtin_amdgcn_s_setprio(1);
#pragma unroll
        for (int mi = 0; mi < 4; ++mi)
#pragma unroll
            for (int ni = 0; ni < 4; ++ni)
                acc[mi][ni] = MFMA16(Ar[mi], Br[ni], acc[mi][ni]);
        __builtin_amdgcn_s_setprio(0);
        __builtin_amdgcn_s_barrier();
        __builtin_amdgcn_sched_barrier(0);

        if (ks + 1 < 32) { stg(2, k0n, cb ^ 1); stg(3, k0n, cb ^ 1); }
#pragma unroll
        for (int mi = 0; mi < 4; ++mi) Ar[mi] = *(const bf16x8*)(L + aB + 2048 + mi * 512);
        __builtin_amdgcn_s_setprio(1);
#pragma unroll
        for (int mi = 0; mi < 4; ++mi)
#pragma unroll
            for (int ni = 0; ni < 4; ++ni)
                acc[4 + mi][ni] = MFMA16(Ar[mi], Br[ni], acc[4 + mi][ni]);
        __builtin_amdgcn_s_setprio(0);
        __builtin_amdgcn_s_barrier();
        __builtin_amdgcn_sched_barrier(0);
    }

    int sec = n0 >> 10;
    float scq = (sec == 0) ? C1 : 1.0f;
#pragma unroll
    for (int mi = 0; mi < 8; ++mi) {
        int gc = n0 + wm * 128 + mi * 16 + quad * 4;
        int dcol = gc & 1023;
        int h = dcol >> 6, hd = dcol & 63;
#pragma unroll
        for (int ni = 0; ni < 4; ++ni) {
            int gx = m0 + wn * 64 + ni * 16 + l16;
            int b = gx >> 11, n = gx & 2047;
            size_t bh = (size_t)(b * 16 + h);
            if (sec == 2) {
#pragma unroll
                for (int r = 0; r < 4; ++r)
                    Vt[(bh * 64 + hd + r) * 2048 + n] = (bf16_t)acc[mi][ni][r];
            } else {
                bf16x4 pk = { (bf16_t)(acc[mi][ni][0] * scq), (bf16_t)(acc[mi][ni][1] * scq),
                              (bf16_t)(acc[mi][ni][2] * scq), (bf16_t)(acc[mi][ni][3] * scq) };
                bf16_t* dst = (sec == 0 ? Q : Kb);
                *(bf16x4*)(dst + (bh * 2048 + n) * 64 + hd) = pk;
            }
        }
    }
}

// ---------------------------------------------------------------------------
// Flash attention v13: R12 KV=128 structure + dual-pipeline compute (T15):
// QK^T for BOTH 64-KV subtiles issued back-to-back (matrix pipe stays fed
// while sub0 results complete), then exp/pack(sub0) on the VALU overlapping
// QK^T(sub1) latency, PV(sub0), exp/pack(sub1) overlapping PV(sub0), PV(sub1).
// Breaks the serial QK->exp->pack->PV chain that left both pipes <50% busy.
__global__ __launch_bounds__(256) void attn_k(const bf16_t* __restrict__ Q,
                                              const bf16_t* __restrict__ Kb,
                                              const bf16_t* __restrict__ Vt,
                                              const float* __restrict__ cbias,
                                              const float* __restrict__ hacc,
                                              const float* __restrict__ b_fg2,
                                              bf16_t* __restrict__ O) {
    __shared__ __align__(16) bf16_t kbuf[2][2][64 * 64];
    __shared__ __align__(16) bf16_t vbuf[2][2][64 * 64];
    __shared__ __align__(16) float ball[2048];
    int t = threadIdx.x, w = t >> 6, lane = t & 63;
    int l16 = lane & 15, quad = lane >> 4;
    int id = blockIdx.x;                    // 0..511, HW assigns XCD = id % 8
    int xcd = id & 7, slot = id >> 3;       // 64 slots per XCD
    int bh = xcd * 4 + (slot >> 4);         // 4 heads per XCD
    int xblk = slot & 15;                   // 16 q-blocks per head, same XCD
    int b = bh >> 4, h = bh & 15;
    int qa = xblk * 128 + w * 32;
    const bf16_t* Qh = Q + (size_t)bh * 2048 * 64;
    const bf16_t* Kh = Kb + (size_t)bh * 2048 * 64;
    const bf16_t* Vh = Vt + (size_t)bh * 64 * 2048;
    const float* bih = cbias + (size_t)bh * 2048;
    float g = 1.0f / (1.0f + __expf(-(hacc[b] + b_fg2[0])));

    // one-time g-scaled bias row into LDS (published by first lgkm(0)+barrier)
#pragma unroll
    for (int c = 0; c < 2; ++c) {
        float4 v = *(const float4*)(bih + c * 1024 + t * 4);
        float4 sv = { v.x * g, v.y * g, v.z * g, v.w * g };
        *(float4*)(ball + c * 1024 + t * 4) = sv;
    }

    int fb0 = w * 2048, fb1 = fb0 + 1024;   // byte ranges staged by this wave
    int f0 = fb0 + lane * 16, f1 = fb1 + lane * 16;
    int krow0 = f0 >> 7, kch0 = ((f0 >> 4) & 7) ^ (krow0 & 7);
    int krow1 = f1 >> 7, kch1 = ((f1 >> 4) & 7) ^ (krow1 & 7);

    bf16x8 qf[2][2];
#pragma unroll
    for (int qt = 0; qt < 2; ++qt)
#pragma unroll
        for (int dh = 0; dh < 2; ++dh)
            qf[qt][dh] = *(const bf16x8*)(Qh + (size_t)(qa + qt * 16 + l16) * 64 + dh * 32 + quad * 8);

    f32x4 o[2][4] = {};
    f32x4 lacc[2] = {};
    bf16x8 onesb;
#pragma unroll
    for (int i = 0; i < 8; ++i) onesb[i] = (bf16_t)1.0f;
    int swl = l16 & 7;
    int qh = quad >> 1, ql = quad & 1;

    // hoisted per-thread LDS read offsets (elements)
    int bk0 = l16 * 64 + ((quad ^ swl) * 8);
    int bk1 = l16 * 64 + (((4 + quad) ^ swl) * 8);
    int bv0 = l16 * 64 + ql * 4 + ((qh ^ swl) * 8);
    int bv1 = l16 * 64 + ql * 4 + (((2 + qh) ^ swl) * 8);
    int bv2 = l16 * 64 + ql * 4 + (((4 + qh) ^ swl) * 8);
    int bv3 = l16 * 64 + ql * 4 + (((6 + qh) ^ swl) * 8);

    // stage one 64-KV subtile: 4 vmem ops per wave (K2 + V2)
    auto stageSub = [&](int jn, bf16_t* kd, bf16_t* vd) {
        glds16(Kh + (size_t)(jn + krow0) * 64 + kch0 * 8, kd + (fb0 >> 1));
        glds16(Kh + (size_t)(jn + krow1) * 64 + kch1 * 8, kd + (fb1 >> 1));
        glds16(Vh + (size_t)krow0 * 2048 + jn + kch0 * 8, vd + (fb0 >> 1));
        glds16(Vh + (size_t)krow1 * 2048 + jn + kch1 * 8, vd + (fb1 >> 1));
    };
    auto stage = [&](int tile_, int bf) {
        int jn = tile_ * 128;
        stageSub(jn,      &kbuf[bf][0][0], &vbuf[bf][0][0]);
        stageSub(jn + 64, &kbuf[bf][1][0], &vbuf[bf][1][0]);
    };

    // exp2 + pack of one subtile's scores -> bf16 fragments (pure VALU)
    auto exppack = [&](f32x4 (&s)[2][4], bf16x8 (&pf)[2][2]) {
#pragma unroll
        for (int qt = 0; qt < 2; ++qt) {
#pragma unroll
            for (int kt = 0; kt < 4; ++kt)
#pragma unroll
                for (int r = 0; r < 4; ++r)
                    s[qt][kt][r] = __builtin_amdgcn_exp2f(s[qt][kt][r]);
#pragma unroll
            for (int pv = 0; pv < 2; ++pv) {
                bf16x8 tmp;
#pragma unroll
                for (int i = 0; i < 4; ++i) {
                    tmp[i]     = (bf16_t)s[qt][2 * pv][i];
                    tmp[i + 4] = (bf16_t)s[qt][2 * pv + 1][i];
                }
                pf[qt][pv] = tmp;
            }
        }
    };
    // PV + lacc accumulate of one subtile (pure MFMA)
    auto pvacc = [&](const bf16_t* vb, bf16x8 (&pf)[2][2]) {
#pragma unroll
        for (int qt = 0; qt < 2; ++qt) {
            lacc[qt] = MFMA16(pf[qt][0], onesb, lacc[qt]);
            lacc[qt] = MFMA16(pf[qt][1], onesb, lacc[qt]);
        }
#pragma unroll
        for (int dt = 0; dt < 4; ++dt) {
            bf16x4 va0 = *(const bf16x4*)(vb + dt * 1024 + bv0);
            bf16x4 vc0 = *(const bf16x4*)(vb + dt * 1024 + bv1);
            bf16x8 vf0 = __builtin_shufflevector(va0, vc0, 0, 1, 2, 3, 4, 5, 6, 7);
            bf16x4 va1 = *(const bf16x4*)(vb + dt * 1024 + bv2);
            bf16x4 vc1 = *(const bf16x4*)(vb + dt * 1024 + bv3);
            bf16x8 vf1 = __builtin_shufflevector(va1, vc1, 0, 1, 2, 3, 4, 5, 6, 7);
#pragma unroll
            for (int qt = 0; qt < 2; ++qt) {
                o[qt][dt] = MFMA16(pf[qt][0], vf0, o[qt][dt]);
                o[qt][dt] = MFMA16(pf[qt][1], vf1, o[qt][dt]);
            }
        }
    };

    stage(0, 0);

    for (int it = 0; it < 16; ++it) {
        int sel = it & 1;
        asm volatile("s_waitcnt lgkmcnt(0)" ::: "memory");
        __builtin_amdgcn_s_barrier();            // everyone done reading buf[sel^1]
        if (it + 1 < 16) {
            stage(it + 1, sel ^ 1);              // outstanding: 16
            asm volatile("s_waitcnt vmcnt(8)" ::: "memory");   // tile-it loads done
        } else {
            asm volatile("s_waitcnt vmcnt(0)" ::: "memory");
        }
        __builtin_amdgcn_s_barrier();            // tile-it data visible to all waves
        __builtin_amdgcn_sched_barrier(0);

        // ---- phase A: QK^T for BOTH subtiles (fills matrix pipe)
        f32x4 s[2][2][4];                        // [sub][qt][kt]
        __builtin_amdgcn_s_setprio(1);
#pragma unroll
        for (int sub = 0; sub < 2; ++sub) {
            int j0 = it * 128 + sub * 64;
            const bf16_t* kb = &kbuf[sel][sub][0];
#pragma unroll
            for (int kt = 0; kt < 4; ++kt) {
                f32x4 bi = *(const f32x4*)(ball + j0 + kt * 16 + quad * 4);
                bf16x8 kf0 = *(const bf16x8*)(kb + kt * 1024 + bk0);
                bf16x8 kf1 = *(const bf16x8*)(kb + kt * 1024 + bk1);
#pragma unroll
                for (int qt = 0; qt < 2; ++qt) {
                    s[sub][qt][kt] = MFMA16(kf0, qf[qt][0], bi);
                    s[sub][qt][kt] = MFMA16(kf1, qf[qt][1], s[sub][qt][kt]);
                }
            }
        }
        __builtin_amdgcn_s_setprio(0);

        // ---- phase B: exp/pack(sub0) overlaps QK(sub1) tail; PV(sub0);
        //      exp/pack(sub1) overlaps PV(sub0); PV(sub1).
        bf16x8 pf0[2][2], pf1[2][2];
        exppack(s[0], pf0);
        __builtin_amdgcn_s_setprio(1);
        pvacc(&vbuf[sel][0][0], pf0);
        __builtin_amdgcn_s_setprio(0);
        exppack(s[1], pf1);
        __builtin_amdgcn_s_setprio(1);
        pvacc(&vbuf[sel][1][0], pf1);
        __builtin_amdgcn_s_setprio(0);
    }

#pragma unroll
    for (int qt = 0; qt < 2; ++qt) {
        f32x4 rinv;
#pragma unroll
        for (int r = 0; r < 4; ++r) rinv[r] = 1.0f / lacc[qt][r];
#pragma unroll
        for (int dt = 0; dt < 4; ++dt)
#pragma unroll
            for (int r = 0; r < 4; ++r) {
                int row = qa + qt * 16 + quad * 4 + r;
                O[(size_t)(b * 2048 + row) * 1024 + h * 64 + dt * 16 + l16] =
                    (bf16_t)(o[qt][dt][r] * rinv[r]);
            }
    }
}

// ---------------------------------------------------------------------------
// out GEMM: R5 single-buffer __syncthreads form (best-measured total).
__global__ __launch_bounds__(256) void out_gemm(const bf16_t* __restrict__ A,
                                                const bf16_t* __restrict__ Wt,
                                                const float* __restrict__ bias,
                                                float* __restrict__ Cout) {
    __shared__ __align__(16) bf16_t At[128 * 32];
    __shared__ __align__(16) bf16_t Bt[128 * 32];
    int t = threadIdx.x, w = t >> 6, lane = t & 63;
    int l16 = lane & 15, quad = lane >> 4;
    int wm = w & 1, wx = w >> 1;
    int m0 = blockIdx.x * 128;
    int n0 = blockIdx.y * 128;
    f32x4 acc[4][4] = {};
    int sw = (l16 >> 2) & 3;

    for (int k0 = 0; k0 < 1024; k0 += 32) {
#pragma unroll
        for (int i = 0; i < 2; ++i) {
            int fb = i * 4096 + w * 1024;
            int f = fb + lane * 16;
            int row = f >> 6;
            int ch = (f >> 4) & 3;
            int sc = ch ^ ((row >> 2) & 3);
            glds16(Wt + (size_t)(n0 + row) * 1024 + k0 + sc * 8, At + (fb >> 1));
            glds16(A + (size_t)(m0 + row) * 1024 + k0 + sc * 8, Bt + (fb >> 1));
        }
        __syncthreads();
        bf16x8 afr[4], bfr[4];
#pragma unroll
        for (int mi = 0; mi < 4; ++mi)
            afr[mi] = *(const bf16x8*)(At + (wm * 64 + mi * 16 + l16) * 32 + ((quad ^ sw) * 8));
#pragma unroll
        for (int ni = 0; ni < 4; ++ni)
            bfr[ni] = *(const bf16x8*)(Bt + (wx * 64 + ni * 16 + l16) * 32 + ((quad ^ sw) * 8));
#pragma unroll
        for (int mi = 0; mi < 4; ++mi)
#pragma unroll
            for (int ni = 0; ni < 4; ++ni)
                acc[mi][ni] = MFMA16(afr[mi], bfr[ni], acc[mi][ni]);
        __syncthreads();
    }

#pragma unroll
    for (int mi = 0; mi < 4; ++mi) {
        int gc = n0 + wm * 64 + mi * 16 + quad * 4;
        float4 bv = *(const float4*)(bias + gc);
#pragma unroll
        for (int ni = 0; ni < 4; ++ni) {
            int gx = m0 + wx * 64 + ni * 16 + l16;
            float4 ov = { acc[mi][ni][0] + bv.x, acc[mi][ni][1] + bv.y,
                          acc[mi][ni][2] + bv.z, acc[mi][ni][3] + bv.w };
            *(float4*)(Cout + (size_t)gx * 1024 + gc) = ov;
        }
    }
}

// ---------------------------------------------------------------------------
extern "C" void kernel_launch(void* const* d_in, const int* in_sizes, int n_in,
                              void* d_out, int out_size, void* d_ws, size_t ws_size,
                              hipStream_t stream) {
    const float* x     = (const float*)d_in[0];
    const float* cov   = (const float*)d_in[1];
    const float* w_qkv = (const float*)d_in[2];
    const float* w_out = (const float*)d_in[3];
    const float* b_out = (const float*)d_in[4];
    const float* w_ce1 = (const float*)d_in[5];
    const float* b_ce1 = (const float*)d_in[6];
    const float* w_ce2 = (const float*)d_in[7];
    const float* b_ce2 = (const float*)d_in[8];
    const float* w_fg1 = (const float*)d_in[9];
    const float* b_fg1 = (const float*)d_in[10];
    const float* w_fg2 = (const float*)d_in[11];
    const float* b_fg2 = (const float*)d_in[12];

    char* ws = (char*)d_ws;
    bf16_t* Wt     = (bf16_t*)(ws);              // 3072x1024
    bf16_t* WoT    = (bf16_t*)(ws + 6291456);    // 1024x1024
    bf16_t* Xb     = (bf16_t*)(ws + 8388608);    // 4096x1024
    bf16_t* Qb     = (bf16_t*)(ws + 16777216);   // (2,16,2048,64)
    bf16_t* Kbb    = (bf16_t*)(ws + 25165824);   // (2,16,2048,64)
    bf16_t* Vt     = (bf16_t*)(ws + 33554432);   // (2,16,64,2048)
    bf16_t* Ob     = (bf16_t*)(ws + 41943040);   // (4096,1024)
    float*  pooled = (float*)(ws + 50331648);    // 2x1024 f32
    float*  hacc   = (float*)(ws + 50339840);    // 2 f32 (contiguous after pooled)
    float*  biasb  = (float*)(ws + 50340096);    // 2x16x2048 f32 (no g applied)

    hipMemsetAsync(pooled, 0, 8200, stream);
    prep<<<1344, 256, 0, stream>>>(x, Xb, w_qkv, Wt, w_out, WoT, pooled,
                                   cov, w_ce1, b_ce1, w_ce2, b_ce2, biasb);
    qkv_gemm<<<dim3(16, 13), 512, 0, stream>>>(Xb, Wt, Qb, Kbb, Vt,
                                               pooled, w_fg1, b_fg1, w_fg2, hacc);
    attn_k<<<512, 256, 0, stream>>>(Qb, Kbb, Vt, biasb, hacc, b_fg2, Ob);
    out_gemm<<<dim3(32, 8), 256, 0, stream>>>(Ob, WoT, b_out, (float*)d_out);
}

// Round 14
// 227.573 us; speedup vs baseline: 1.0050x; 1.0002x over previous
//
#include <hip/hip_runtime.h>
#include <math.h>

typedef __bf16 bf16_t;
typedef __bf16 bf16x8 __attribute__((ext_vector_type(8)));
typedef __bf16 bf16x4 __attribute__((ext_vector_type(4)));
typedef float f32x4 __attribute__((ext_vector_type(4)));

#define MFMA16(a, b, c) __builtin_amdgcn_mfma_f32_16x16x32_bf16((a), (b), (c), 0, 0, 0)

constexpr int Bc = 2, Nc = 2048, Dc = 1024, Hc = 16, HDc = 64;
constexpr float C1 = 0.18033688011112042f;     // 0.125 * log2(e), folded into Q at qkv epilogue
constexpr float LOG2E = 1.4426950408889634f;

// async global->LDS, 16B per lane; LDS base must be wave-uniform (HW adds lane*16)
__device__ __forceinline__ void glds16(const bf16_t* g, bf16_t* l) {
    __builtin_amdgcn_global_load_lds(
        (const __attribute__((address_space(1))) unsigned int*)g,
        (__attribute__((address_space(3))) unsigned int*)l, 16, 0, 0);
}

// ---------------------------------------------------------------------------
__device__ __forceinline__ void tr64_body(const float* __restrict__ src,
                                          bf16_t* __restrict__ dst, int R, int C,
                                          int bx, int by, bf16_t* tile, int t) {
    int r0 = by * 64, c0 = bx * 64;
    int cl = t & 63, rl = t >> 6;
#pragma unroll
    for (int p = 0; p < 16; ++p) {
        int r = p * 4 + rl;
        tile[r * 66 + cl] = (bf16_t)src[(size_t)(r0 + r) * C + c0 + cl];
    }
    __syncthreads();
#pragma unroll
    for (int p = 0; p < 16; ++p) {
        int r = p * 4 + rl;
        dst[(size_t)(c0 + r) * R + r0 + cl] = tile[cl * 66 + r];
    }
}

// ---------------------------------------------------------------------------
// Fused prep (R9/R10 form). Long-pole jobs get the LOWEST block ids.
__global__ __launch_bounds__(256) void prep(const float* __restrict__ x,
                                            bf16_t* __restrict__ Xb,
                                            const float* __restrict__ w_qkv,
                                            bf16_t* __restrict__ Wt,
                                            const float* __restrict__ w_out,
                                            bf16_t* __restrict__ WoT,
                                            float* __restrict__ pooled,
                                            const float* __restrict__ coverage,
                                            const float* __restrict__ w_ce1,
                                            const float* __restrict__ b_ce1,
                                            const float* __restrict__ w_ce2,
                                            const float* __restrict__ b_ce2,
                                            float* __restrict__ cbias) {
    __shared__ __align__(16) float smem[8768];   // 35 KB, aliased per job
    int bid = blockIdx.x, t = threadIdx.x;

    if (bid < 64) {                         // ---- coverage-bias (no gate g)
        float* w1s = smem;                  // 256
        float* b1s = smem + 256;            // 256
        float* w2s = smem + 512;            // 256*16
        float* part = smem + 4608;          // 64 rows x 65 (padded, conflict-free)
        int b = bid >> 5, n0 = (bid & 31) * 64;
        w1s[t] = w_ce1[t];
        b1s[t] = b_ce1[t];
        {
            float4* w2v = (float4*)w2s;
            const float4* g4 = (const float4*)w_ce2;
#pragma unroll
            for (int i = 0; i < 4; ++i) w2v[i * 256 + t] = g4[i * 256 + t];
        }
        __syncthreads();
        int wv = t >> 6, lane2 = t & 63;
        float c = coverage[b * 2048 + n0 + lane2];
        float acc[16];
#pragma unroll
        for (int hh = 0; hh < 16; ++hh) acc[hh] = 0.f;
        for (int jj = 0; jj < 64; ++jj) {
            int j = wv * 64 + jj;
            float tv = fmaf(c, w1s[j], b1s[j]);
            tv = tv / (1.0f + __expf(-tv));   // silu
#pragma unroll
            for (int hh = 0; hh < 16; ++hh)
                acc[hh] = fmaf(tv, w2s[j * 16 + hh], acc[hh]);
        }
#pragma unroll
        for (int hh = 0; hh < 16; ++hh) part[lane2 * 65 + wv * 16 + hh] = acc[hh];
        __syncthreads();
#pragma unroll
        for (int i = 0; i < 4; ++i) {
            int idx = t + i * 256;
            int nl = idx >> 4, hh = idx & 15;
            const float* pr = part + nl * 65 + hh;
            float s = pr[0] + pr[16] + pr[32] + pr[48];
            cbias[((size_t)b * 16 + hh) * 2048 + n0 + nl] = LOG2E * (s + b_ce2[hh]);
        }
    } else if (bid < 832) {                 // ---- transpose w_qkv
        int bb = bid - 64;
        tr64_body(w_qkv, Wt, 1024, 3072, bb % 48, bb / 48, (bf16_t*)smem, t);
    } else if (bid < 1088) {                // ---- transpose w_out
        int bb = bid - 832;
        tr64_body(w_out, WoT, 1024, 1024, bb & 15, bb >> 4, (bf16_t*)smem, t);
    } else {                                // ---- f2b + pool: 16 rows per block
        int blk = bid - 1088;               // 0..255
        int b = blk >> 7;
        int rbase = blk * 16;
        int d = t * 4;
        float s0 = 0.f, s1 = 0.f, s2 = 0.f, s3 = 0.f;
        for (int rr = 0; rr < 16; ++rr) {
            size_t off = (size_t)(rbase + rr) * 1024 + d;
            float4 v = *(const float4*)(x + off);
            s0 += v.x; s1 += v.y; s2 += v.z; s3 += v.w;
            bf16x4 o = { (bf16_t)v.x, (bf16_t)v.y, (bf16_t)v.z, (bf16_t)v.w };
            *(bf16x4*)(Xb + off) = o;
        }
        atomicAdd(&pooled[b * 1024 + d + 0], s0);
        atomicAdd(&pooled[b * 1024 + d + 1], s1);
        atomicAdd(&pooled[b * 1024 + d + 2], s2);
        atomicAdd(&pooled[b * 1024 + d + 3], s3);
    }
}

// ---------------------------------------------------------------------------
// QKV GEMM v4 (R11 form, best measured): 256x256 tile, BK=32, 512 threads =
// 8 waves (2M x 4N), acc[8][4]/wave, counted-vmcnt dbuf, 64KB LDS.
// Gate MLP at blockIdx.y == 12. Q pre-scaled by C1.
__global__ __launch_bounds__(512, 2) void qkv_gemm(const bf16_t* __restrict__ Xb,
                                                   const bf16_t* __restrict__ Wt,
                                                   bf16_t* __restrict__ Q,
                                                   bf16_t* __restrict__ Kb,
                                                   bf16_t* __restrict__ Vt,
                                                   const float* __restrict__ pooled,
                                                   const float* __restrict__ w_fg1,
                                                   const float* __restrict__ b_fg1,
                                                   const float* __restrict__ w_fg2,
                                                   float* __restrict__ hacc) {
    __shared__ __align__(16) bf16_t lds[2][16384];   // 64 KB total
    int t = threadIdx.x;

    if (blockIdx.y == 12) {                 // gate MLP: hacc[b] += silu(h_j)*w_fg2[j]
        float* red = (float*)&lds[0][0];
        int blk = blockIdx.x;               // 16 blocks: b = blk>>3, 32 j's each
        int b = blk >> 3, jb = (blk & 7) * 32;
        for (int jj = 0; jj < 32; ++jj) {
            int j = jb + jj;
            int d = t * 2;
            float p = pooled[b * 1024 + d] * w_fg1[d * 256 + j]
                    + pooled[b * 1024 + d + 1] * w_fg1[(d + 1) * 256 + j];
#pragma unroll
            for (int off = 32; off > 0; off >>= 1) p += __shfl_down(p, off);
            if ((t & 63) == 0) red[t >> 6] = p;
            __syncthreads();
            if (t == 0) {
                float s = red[0] + red[1] + red[2] + red[3]
                        + red[4] + red[5] + red[6] + red[7];
                float hj = s * (1.0f / 2048.0f) + b_fg1[j];
                hj = hj / (1.0f + __expf(-hj)); // silu
                atomicAdd(&hacc[b], hj * w_fg2[j]);
            }
            __syncthreads();
        }
        return;
    }

    int w = t >> 6, lane = t & 63;
    int l16 = lane & 15, quad = lane >> 4;
    int wm = w >> 2, wn = w & 3;            // 2M x 4N wave grid
    int m0 = blockIdx.x * 256;              // x-row base
    int n0 = blockIdx.y * 256;              // W-col base
    f32x4 acc[8][4] = {};
    int sw = (l16 >> 2) & 3;
    int cq = (quad ^ sw) * 8;

    int srow[4], ssc[4], sdst[4];
    bool sB[4];
#pragma unroll
    for (int j = 0; j < 4; ++j) {
        int off = w * 4096 + j * 1024 + lane * 16;   // byte in 32KB tile
        bool inB = off >= 16384;
        int o2 = off - (inB ? 16384 : 0);
        int row = o2 >> 6;                           // 64B per 32-k row
        int ch = (o2 >> 4) & 3;
        srow[j] = row;
        ssc[j] = ch ^ ((row >> 2) & 3);
        sB[j] = inB;
        sdst[j] = (w * 4096 + j * 1024) >> 1;        // wave-uniform elem base
    }
    auto stg = [&](int j, int k0, int bf) {
        const bf16_t* src = sB[j] ? Xb + (size_t)(m0 + srow[j]) * 1024
                                  : Wt + (size_t)(n0 + srow[j]) * 1024;
        glds16(src + k0 + ssc[j] * 8, &lds[bf][sdst[j]]);
    };

    int aB = (wm * 128 + l16) * 32 + cq;             // A frag mi at aB + mi*512
    int bB = 8192 + (wn * 64 + l16) * 32 + cq;       // B frag ni at bB + ni*512

    stg(0, 0, 0); stg(1, 0, 0); stg(2, 0, 0); stg(3, 0, 0);

#pragma unroll 1
    for (int ks = 0; ks < 32; ++ks) {
        int cb = ks & 1, k0n = (ks + 1) * 32;
        if (ks + 1 < 32) {
            stg(0, k0n, cb ^ 1); stg(1, k0n, cb ^ 1);           // outstanding: 6
            asm volatile("s_waitcnt vmcnt(2)" ::: "memory");    // tile-ks landed
        } else {
            asm volatile("s_waitcnt vmcnt(0)" ::: "memory");
        }
        __builtin_amdgcn_s_barrier();
        __builtin_amdgcn_sched_barrier(0);

        const bf16_t* L = lds[cb];
        bf16x8 Ar[4], Br[4];
#pragma unroll
        for (int mi = 0; mi < 4; ++mi) Ar[mi] = *(const bf16x8*)(L + aB + mi * 512);
#pragma unroll
        for (int ni = 0; ni < 4; ++ni) Br[ni] = *(const bf16x8*)(L + bB + ni * 512);
        __builtin_amdgcn_s_setprio(1);
#pragma unroll
        for (int mi = 0; mi < 4; ++mi)
#pragma unroll
            for (int ni = 0; ni < 4; ++ni)
                acc[mi][ni] = MFMA16(Ar[mi], Br[ni], acc[mi][ni]);
        __builtin_amdgcn_s_setprio(0);
        __builtin_amdgcn_s_barrier();
        __builtin_amdgcn_sched_barrier(0);

        if (ks + 1 < 32) { stg(2, k0n, cb ^ 1); stg(3, k0n, cb ^ 1); }
#pragma unroll
        for (int mi = 0; mi < 4; ++mi) Ar[mi] = *(const bf16x8*)(L + aB + 2048 + mi * 512);
        __builtin_amdgcn_s_setprio(1);
#pragma unroll
        for (int mi = 0; mi < 4; ++mi)
#pragma unroll
            for (int ni = 0; ni < 4; ++ni)
                acc[4 + mi][ni] = MFMA16(Ar[mi], Br[ni], acc[4 + mi][ni]);
        __builtin_amdgcn_s_setprio(0);
        __builtin_amdgcn_s_barrier();
        __builtin_amdgcn_sched_barrier(0);
    }

    int sec = n0 >> 10;
    float scq = (sec == 0) ? C1 : 1.0f;
#pragma unroll
    for (int mi = 0; mi < 8; ++mi) {
        int gc = n0 + wm * 128 + mi * 16 + quad * 4;
        int dcol = gc & 1023;
        int h = dcol >> 6, hd = dcol & 63;
#pragma unroll
        for (int ni = 0; ni < 4; ++ni) {
            int gx = m0 + wn * 64 + ni * 16 + l16;
            int b = gx >> 11, n = gx & 2047;
            size_t bh = (size_t)(b * 16 + h);
            if (sec == 2) {
#pragma unroll
                for (int r = 0; r < 4; ++r)
                    Vt[(bh * 64 + hd + r) * 2048 + n] = (bf16_t)acc[mi][ni][r];
            } else {
                bf16x4 pk = { (bf16_t)(acc[mi][ni][0] * scq), (bf16_t)(acc[mi][ni][1] * scq),
                              (bf16_t)(acc[mi][ni][2] * scq), (bf16_t)(acc[mi][ni][3] * scq) };
                bf16_t* dst = (sec == 0 ? Q : Kb);
                *(bf16x4*)(dst + (bh * 2048 + n) * 64 + hd) = pk;
            }
        }
    }
}

// ---------------------------------------------------------------------------
// Flash attention v13 (R13 form, best measured): KV=128/iter, dual-pipeline
// compute (QK both subtiles -> exp/pack overlapped with PV), counted vmcnt,
// g-scaled bias row in LDS once, chunked XCD mapping.
__global__ __launch_bounds__(256) void attn_k(const bf16_t* __restrict__ Q,
                                              const bf16_t* __restrict__ Kb,
                                              const bf16_t* __restrict__ Vt,
                                              const float* __restrict__ cbias,
                                              const float* __restrict__ hacc,
                                              const float* __restrict__ b_fg2,
                                              bf16_t* __restrict__ O) {
    __shared__ __align__(16) bf16_t kbuf[2][2][64 * 64];
    __shared__ __align__(16) bf16_t vbuf[2][2][64 * 64];
    __shared__ __align__(16) float ball[2048];
    int t = threadIdx.x, w = t >> 6, lane = t & 63;
    int l16 = lane & 15, quad = lane >> 4;
    int id = blockIdx.x;                    // 0..511, HW assigns XCD = id % 8
    int xcd = id & 7, slot = id >> 3;       // 64 slots per XCD
    int bh = xcd * 4 + (slot >> 4);         // 4 heads per XCD
    int xblk = slot & 15;                   // 16 q-blocks per head, same XCD
    int b = bh >> 4, h = bh & 15;
    int qa = xblk * 128 + w * 32;
    const bf16_t* Qh = Q + (size_t)bh * 2048 * 64;
    const bf16_t* Kh = Kb + (size_t)bh * 2048 * 64;
    const bf16_t* Vh = Vt + (size_t)bh * 64 * 2048;
    const float* bih = cbias + (size_t)bh * 2048;
    float g = 1.0f / (1.0f + __expf(-(hacc[b] + b_fg2[0])));

    // one-time g-scaled bias row into LDS (published by first lgkm(0)+barrier)
#pragma unroll
    for (int c = 0; c < 2; ++c) {
        float4 v = *(const float4*)(bih + c * 1024 + t * 4);
        float4 sv = { v.x * g, v.y * g, v.z * g, v.w * g };
        *(float4*)(ball + c * 1024 + t * 4) = sv;
    }

    int fb0 = w * 2048, fb1 = fb0 + 1024;   // byte ranges staged by this wave
    int f0 = fb0 + lane * 16, f1 = fb1 + lane * 16;
    int krow0 = f0 >> 7, kch0 = ((f0 >> 4) & 7) ^ (krow0 & 7);
    int krow1 = f1 >> 7, kch1 = ((f1 >> 4) & 7) ^ (krow1 & 7);

    bf16x8 qf[2][2];
#pragma unroll
    for (int qt = 0; qt < 2; ++qt)
#pragma unroll
        for (int dh = 0; dh < 2; ++dh)
            qf[qt][dh] = *(const bf16x8*)(Qh + (size_t)(qa + qt * 16 + l16) * 64 + dh * 32 + quad * 8);

    f32x4 o[2][4] = {};
    f32x4 lacc[2] = {};
    bf16x8 onesb;
#pragma unroll
    for (int i = 0; i < 8; ++i) onesb[i] = (bf16_t)1.0f;
    int swl = l16 & 7;
    int qh = quad >> 1, ql = quad & 1;

    // hoisted per-thread LDS read offsets (elements)
    int bk0 = l16 * 64 + ((quad ^ swl) * 8);
    int bk1 = l16 * 64 + (((4 + quad) ^ swl) * 8);
    int bv0 = l16 * 64 + ql * 4 + ((qh ^ swl) * 8);
    int bv1 = l16 * 64 + ql * 4 + (((2 + qh) ^ swl) * 8);
    int bv2 = l16 * 64 + ql * 4 + (((4 + qh) ^ swl) * 8);
    int bv3 = l16 * 64 + ql * 4 + (((6 + qh) ^ swl) * 8);

    // stage one 64-KV subtile: 4 vmem ops per wave (K2 + V2)
    auto stageSub = [&](int jn, bf16_t* kd, bf16_t* vd) {
        glds16(Kh + (size_t)(jn + krow0) * 64 + kch0 * 8, kd + (fb0 >> 1));
        glds16(Kh + (size_t)(jn + krow1) * 64 + kch1 * 8, kd + (fb1 >> 1));
        glds16(Vh + (size_t)krow0 * 2048 + jn + kch0 * 8, vd + (fb0 >> 1));
        glds16(Vh + (size_t)krow1 * 2048 + jn + kch1 * 8, vd + (fb1 >> 1));
    };
    auto stage = [&](int tile_, int bf) {
        int jn = tile_ * 128;
        stageSub(jn,      &kbuf[bf][0][0], &vbuf[bf][0][0]);
        stageSub(jn + 64, &kbuf[bf][1][0], &vbuf[bf][1][0]);
    };

    // exp2 + pack of one subtile's scores -> bf16 fragments (pure VALU)
    auto exppack = [&](f32x4 (&s)[2][4], bf16x8 (&pf)[2][2]) {
#pragma unroll
        for (int qt = 0; qt < 2; ++qt) {
#pragma unroll
            for (int kt = 0; kt < 4; ++kt)
#pragma unroll
                for (int r = 0; r < 4; ++r)
                    s[qt][kt][r] = __builtin_amdgcn_exp2f(s[qt][kt][r]);
#pragma unroll
            for (int pv = 0; pv < 2; ++pv) {
                bf16x8 tmp;
#pragma unroll
                for (int i = 0; i < 4; ++i) {
                    tmp[i]     = (bf16_t)s[qt][2 * pv][i];
                    tmp[i + 4] = (bf16_t)s[qt][2 * pv + 1][i];
                }
                pf[qt][pv] = tmp;
            }
        }
    };
    // PV + lacc accumulate of one subtile (pure MFMA)
    auto pvacc = [&](const bf16_t* vb, bf16x8 (&pf)[2][2]) {
#pragma unroll
        for (int qt = 0; qt < 2; ++qt) {
            lacc[qt] = MFMA16(pf[qt][0], onesb, lacc[qt]);
            lacc[qt] = MFMA16(pf[qt][1], onesb, lacc[qt]);
        }
#pragma unroll
        for (int dt = 0; dt < 4; ++dt) {
            bf16x4 va0 = *(const bf16x4*)(vb + dt * 1024 + bv0);
            bf16x4 vc0 = *(const bf16x4*)(vb + dt * 1024 + bv1);
            bf16x8 vf0 = __builtin_shufflevector(va0, vc0, 0, 1, 2, 3, 4, 5, 6, 7);
            bf16x4 va1 = *(const bf16x4*)(vb + dt * 1024 + bv2);
            bf16x4 vc1 = *(const bf16x4*)(vb + dt * 1024 + bv3);
            bf16x8 vf1 = __builtin_shufflevector(va1, vc1, 0, 1, 2, 3, 4, 5, 6, 7);
#pragma unroll
            for (int qt = 0; qt < 2; ++qt) {
                o[qt][dt] = MFMA16(pf[qt][0], vf0, o[qt][dt]);
                o[qt][dt] = MFMA16(pf[qt][1], vf1, o[qt][dt]);
            }
        }
    };

    stage(0, 0);

    for (int it = 0; it < 16; ++it) {
        int sel = it & 1;
        asm volatile("s_waitcnt lgkmcnt(0)" ::: "memory");
        __builtin_amdgcn_s_barrier();            // everyone done reading buf[sel^1]
        if (it + 1 < 16) {
            stage(it + 1, sel ^ 1);              // outstanding: 16
            asm volatile("s_waitcnt vmcnt(8)" ::: "memory");   // tile-it loads done
        } else {
            asm volatile("s_waitcnt vmcnt(0)" ::: "memory");
        }
        __builtin_amdgcn_s_barrier();            // tile-it data visible to all waves
        __builtin_amdgcn_sched_barrier(0);

        // ---- phase A: QK^T for BOTH subtiles (fills matrix pipe)
        f32x4 s[2][2][4];                        // [sub][qt][kt]
        __builtin_amdgcn_s_setprio(1);
#pragma unroll
        for (int sub = 0; sub < 2; ++sub) {
            int j0 = it * 128 + sub * 64;
            const bf16_t* kb = &kbuf[sel][sub][0];
#pragma unroll
            for (int kt = 0; kt < 4; ++kt) {
                f32x4 bi = *(const f32x4*)(ball + j0 + kt * 16 + quad * 4);
                bf16x8 kf0 = *(const bf16x8*)(kb + kt * 1024 + bk0);
                bf16x8 kf1 = *(const bf16x8*)(kb + kt * 1024 + bk1);
#pragma unroll
                for (int qt = 0; qt < 2; ++qt) {
                    s[sub][qt][kt] = MFMA16(kf0, qf[qt][0], bi);
                    s[sub][qt][kt] = MFMA16(kf1, qf[qt][1], s[sub][qt][kt]);
                }
            }
        }
        __builtin_amdgcn_s_setprio(0);

        // ---- phase B: exp/pack(sub0) overlaps QK(sub1) tail; PV(sub0);
        //      exp/pack(sub1) overlaps PV(sub0); PV(sub1).
        bf16x8 pf0[2][2], pf1[2][2];
        exppack(s[0], pf0);
        __builtin_amdgcn_s_setprio(1);
        pvacc(&vbuf[sel][0][0], pf0);
        __builtin_amdgcn_s_setprio(0);
        exppack(s[1], pf1);
        __builtin_amdgcn_s_setprio(1);
        pvacc(&vbuf[sel][1][0], pf1);
        __builtin_amdgcn_s_setprio(0);
    }

#pragma unroll
    for (int qt = 0; qt < 2; ++qt) {
        f32x4 rinv;
#pragma unroll
        for (int r = 0; r < 4; ++r) rinv[r] = 1.0f / lacc[qt][r];
#pragma unroll
        for (int dt = 0; dt < 4; ++dt)
#pragma unroll
            for (int r = 0; r < 4; ++r) {
                int row = qa + qt * 16 + quad * 4 + r;
                O[(size_t)(b * 2048 + row) * 1024 + h * 64 + dt * 16 + l16] =
                    (bf16_t)(o[qt][dt][r] * rinv[r]);
            }
    }
}

// ---------------------------------------------------------------------------
// out GEMM v2: 128x64 tile, grid (32,16) = 512 blocks = 2 blocks/CU (was
// 1 block/CU = 1 wave/SIMD, the R8 pathology). R6-style counted-vmcnt dbuf:
// 3 stage-ops/wave (A-panel 8KB + W-panel 4KB), vmcnt(3), two raw barriers.
// LDS 24KB. acc[2][4]/wave: waves split (wm = row-half 64, wx = col-half 32).
__global__ __launch_bounds__(256) void out_gemm(const bf16_t* __restrict__ A,
                                                const bf16_t* __restrict__ Wt,
                                                const float* __restrict__ bias,
                                                float* __restrict__ Cout) {
    __shared__ __align__(16) bf16_t At[2][64 * 32];    // W-cols panel, 4KB/buf
    __shared__ __align__(16) bf16_t Bt[2][128 * 32];   // x-rows panel, 8KB/buf
    int t = threadIdx.x, w = t >> 6, lane = t & 63;
    int l16 = lane & 15, quad = lane >> 4;
    int wm = w & 1, wx = w >> 1;            // wm: row-half (64), wx: col-half (32)
    int m0 = blockIdx.x * 128;              // output rows
    int n0 = blockIdx.y * 64;               // output cols
    f32x4 acc[2][4] = {};
    int sw = (l16 >> 2) & 3;
    int cq = (quad ^ sw) * 8;

    // staging decomposition (chunk-XOR within 64B k-rows)
    // A-panel (At, 4KB): wave stages bytes [w*1024, +1024)
    int ao = w * 1024 + lane * 16;
    int arow = ao >> 6, ach = (ao >> 4) & 3;
    int asc = ach ^ ((arow >> 2) & 3);
    int adst = (w * 1024) >> 1;
    // B-panel (Bt, 8KB): wave stages bytes [w*2048, +2048), 2 ops
    int brow[2], bsc[2], bdst[2];
#pragma unroll
    for (int i = 0; i < 2; ++i) {
        int bo = w * 2048 + i * 1024 + lane * 16;
        int row = bo >> 6, ch = (bo >> 4) & 3;
        brow[i] = row;
        bsc[i] = ch ^ ((row >> 2) & 3);
        bdst[i] = (w * 2048 + i * 1024) >> 1;
    }
    auto stage = [&](int k0, int bf) {      // 3 vmem ops per wave
        glds16(Wt + (size_t)(n0 + arow) * 1024 + k0 + asc * 8, At[bf] + adst);
#pragma unroll
        for (int i = 0; i < 2; ++i)
            glds16(A + (size_t)(m0 + brow[i]) * 1024 + k0 + bsc[i] * 8, Bt[bf] + bdst[i]);
    };

    stage(0, 0);
    for (int ks = 0; ks < 32; ++ks) {
        int sel = ks & 1;
        asm volatile("s_waitcnt lgkmcnt(0)" ::: "memory");
        __builtin_amdgcn_s_barrier();            // everyone done reading buf[sel^1]
        if (ks + 1 < 32) {
            stage((ks + 1) * 32, sel ^ 1);       // outstanding: 6
            asm volatile("s_waitcnt vmcnt(3)" ::: "memory");   // tile-ks loads done
        } else {
            asm volatile("s_waitcnt vmcnt(0)" ::: "memory");
        }
        __builtin_amdgcn_s_barrier();
        __builtin_amdgcn_sched_barrier(0);

        const bf16_t* Ab = At[sel];
        const bf16_t* Bb = Bt[sel];
        bf16x8 afr[2], bfr[4];
#pragma unroll
        for (int mi = 0; mi < 2; ++mi)
            afr[mi] = *(const bf16x8*)(Ab + (wx * 32 + mi * 16 + l16) * 32 + cq);
#pragma unroll
        for (int ni = 0; ni < 4; ++ni)
            bfr[ni] = *(const bf16x8*)(Bb + (wm * 64 + ni * 16 + l16) * 32 + cq);
        __builtin_amdgcn_s_setprio(1);
#pragma unroll
        for (int mi = 0; mi < 2; ++mi)
#pragma unroll
            for (int ni = 0; ni < 4; ++ni)
                acc[mi][ni] = MFMA16(afr[mi], bfr[ni], acc[mi][ni]);
        __builtin_amdgcn_s_setprio(0);
    }

#pragma unroll
    for (int mi = 0; mi < 2; ++mi) {
        int gc = n0 + wx * 32 + mi * 16 + quad * 4;
        float4 bv = *(const float4*)(bias + gc);
#pragma unroll
        for (int ni = 0; ni < 4; ++ni) {
            int gx = m0 + wm * 64 + ni * 16 + l16;
            float4 ov = { acc[mi][ni][0] + bv.x, acc[mi][ni][1] + bv.y,
                          acc[mi][ni][2] + bv.z, acc[mi][ni][3] + bv.w };
            *(float4*)(Cout + (size_t)gx * 1024 + gc) = ov;
        }
    }
}

// ---------------------------------------------------------------------------
extern "C" void kernel_launch(void* const* d_in, const int* in_sizes, int n_in,
                              void* d_out, int out_size, void* d_ws, size_t ws_size,
                              hipStream_t stream) {
    const float* x     = (const float*)d_in[0];
    const float* cov   = (const float*)d_in[1];
    const float* w_qkv = (const float*)d_in[2];
    const float* w_out = (const float*)d_in[3];
    const float* b_out = (const float*)d_in[4];
    const float* w_ce1 = (const float*)d_in[5];
    const float* b_ce1 = (const float*)d_in[6];
    const float* w_ce2 = (const float*)d_in[7];
    const float* b_ce2 = (const float*)d_in[8];
    const float* w_fg1 = (const float*)d_in[9];
    const float* b_fg1 = (const float*)d_in[10];
    const float* w_fg2 = (const float*)d_in[11];
    const float* b_fg2 = (const float*)d_in[12];

    char* ws = (char*)d_ws;
    bf16_t* Wt     = (bf16_t*)(ws);              // 3072x1024
    bf16_t* WoT    = (bf16_t*)(ws + 6291456);    // 1024x1024
    bf16_t* Xb     = (bf16_t*)(ws + 8388608);    // 4096x1024
    bf16_t* Qb     = (bf16_t*)(ws + 16777216);   // (2,16,2048,64)
    bf16_t* Kbb    = (bf16_t*)(ws + 25165824);   // (2,16,2048,64)
    bf16_t* Vt     = (bf16_t*)(ws + 33554432);   // (2,16,64,2048)
    bf16_t* Ob     = (bf16_t*)(ws + 41943040);   // (4096,1024)
    float*  pooled = (float*)(ws + 50331648);    // 2x1024 f32
    float*  hacc   = (float*)(ws + 50339840);    // 2 f32 (contiguous after pooled)
    float*  biasb  = (float*)(ws + 50340096);    // 2x16x2048 f32 (no g applied)

    hipMemsetAsync(pooled, 0, 8200, stream);
    prep<<<1344, 256, 0, stream>>>(x, Xb, w_qkv, Wt, w_out, WoT, pooled,
                                   cov, w_ce1, b_ce1, w_ce2, b_ce2, biasb);
    qkv_gemm<<<dim3(16, 13), 512, 0, stream>>>(Xb, Wt, Qb, Kbb, Vt,
                                               pooled, w_fg1, b_fg1, w_fg2, hacc);
    attn_k<<<512, 256, 0, stream>>>(Qb, Kbb, Vt, biasb, hacc, b_fg2, Ob);
    out_gemm<<<dim3(32, 16), 256, 0, stream>>>(Ob, WoT, b_out, (float*)d_out);
}